// Round 7
// baseline (242.244 us; speedup 1.0000x reference)
//
#include <hip/hip_runtime.h>
#include <hip/hip_bf16.h>

#define IN_DIM    1024
#define HEAD_DIM  64
#define NUM_HEADS 16
#define SEQ       4096

// 1/sqrt(64) * log2(e), folded into Q (fp32, pre-bf16-cast). Softmax computed
// with exp2 (v_exp_f32 IS 2^x) -> no per-element ln2 prescale mul in attn.
#define QSCALE 0.18033688011112042f

typedef __bf16 bf16;
typedef __attribute__((ext_vector_type(4))) __bf16 bf16x4;
typedef __attribute__((ext_vector_type(8))) __bf16 bf16x8;
typedef __attribute__((ext_vector_type(4))) float floatx4;
typedef __attribute__((ext_vector_type(16))) float floatx16;
typedef __attribute__((ext_vector_type(4))) unsigned uint32x4;

__device__ __forceinline__ void async16(bf16* lds, const bf16* g) {
    __builtin_amdgcn_global_load_lds(
        (const __attribute__((address_space(1))) unsigned int*)g,
        (__attribute__((address_space(3))) unsigned int*)lds, 16, 0, 0);
}

__device__ __forceinline__ unsigned cvtpk_bf16(float lo, float hi) {
    unsigned r;
    asm("v_cvt_pk_bf16_f32 %0, %1, %2" : "=v"(r) : "v"(lo), "v"(hi));
    return r;
}

// v_permlane32_swap_b32 vdst, vsrc (CDNA4): vdst[32:63] <-> vsrc[0:31]
__device__ __forceinline__ void permswap(unsigned& a, unsigned& b) {
    asm("v_permlane32_swap_b32 %0, %1" : "+v"(a), "+v"(b));
}

// ---------------------------------------------------------------------------
// ws layout: hb @0 (8MB) | Wt @8MB (6MB, n-major) | Qb @14MB | Kb @22MB | Vt @30MB
// ---------------------------------------------------------------------------

__global__ void mha_conv_h(const float* __restrict__ h, bf16* __restrict__ hb) {
    int i = blockIdx.x * blockDim.x + threadIdx.x;
    float4 v = ((const float4*)h)[i];
    bf16x4 r;
    r[0] = (bf16)v.x; r[1] = (bf16)v.y; r[2] = (bf16)v.z; r[3] = (bf16)v.w;
    ((bf16x4*)hb)[i] = r;
}

__global__ void mha_conv_wt(const float* __restrict__ Wq, const float* __restrict__ Wk,
                            const float* __restrict__ Wv, bf16* __restrict__ Wt) {
    __shared__ bf16 tile[64][65];
    const int mat = blockIdx.z;
    const float* W = (mat == 0) ? Wq : (mat == 1) ? Wk : Wv;
    const int k0 = blockIdx.y * 64, n0 = blockIdx.x * 64;
    const int tn = threadIdx.x & 63, tq = threadIdx.x >> 6;
#pragma unroll
    for (int i = 0; i < 16; ++i) {
        int kk = tq + i * 4;
        tile[kk][tn] = (bf16)W[(size_t)(k0 + kk) * 1024 + n0 + tn];
    }
    __syncthreads();
#pragma unroll
    for (int i = 0; i < 16; ++i) {
        int nn = tq + i * 4;
        Wt[((size_t)mat << 20) + (size_t)(n0 + nn) * 1024 + k0 + tn] = tile[tn][nn];
    }
}

// ---------------------------------------------------------------------------
// QKV GEMM v7: 256x256 tile, BK=64, 8 waves (2M x 4N), double-buffered LDS
// (128KB), phase-interleaved K-loop with counted vmcnt (T3+T4) + setprio (T5).
// R6 post-mortem: the 2-phase 128x128 structure is at ITS shape ceiling
// (~286 TF here, matching m102's mid-shape curve); epilogue experiments are
// noise.  The proven lever is the 8-phase 256^2 combo (1563 TF @4k).
// This is that template rebuilt from session-verified parts:
//  * staging: global_load_lds, linear LDS dest, source-XOR-swizzled chunks
//    (same family as the verified attn kernel; conflict-free in 16-lane groups)
//  * 4 phases per K-tile (ks x mt-half), 16 MFMA each, s_setprio around MFMA
//  * stage 1 half-tile per phase into buf[(u+1)&1]; safe because buf[(u+1)&1]
//    was last read in iter u-1, sealed by its final barrier
//  * vmcnt(2) ONCE per K-tile (phase 0): drains the 4 half-tiles staged last
//    iter, keeps this phase's 2 loads in flight; vmcnt(0) only at u=15
// Per-wave output 128x64 = acc[8][4] 16x16 tiles (128 VGPR).
// Grid 16x12 = 192 blocks (1/CU).  Epilogue = R4-verified scalar stores.
// ---------------------------------------------------------------------------
#define GPHASE(KS, MH, READBF)                                                 \
    {                                                                          \
        bf16x8 af[4];                                                          \
        _Pragma("unroll")                                                      \
        for (int mtl = 0; mtl < 4; ++mtl)                                      \
            af[mtl] = *(const bf16x8*)(&Abuf[cb][                              \
                (wm * 128 + ((MH) * 4 + mtl) * 16 + l16) * 64                  \
                + ((((KS) * 4 + quad) ^ swz) * 8)]);                           \
        if (READBF) {                                                          \
            _Pragma("unroll")                                                  \
            for (int nt = 0; nt < 4; ++nt)                                     \
                bfr[nt] = *(const bf16x8*)(&Bbuf[cb][                          \
                    (wn * 64 + nt * 16 + l16) * 64                             \
                    + ((((KS) * 4 + quad) ^ swz) * 8)]);                       \
        }                                                                      \
        __builtin_amdgcn_s_setprio(1);                                         \
        _Pragma("unroll")                                                      \
        for (int mtl = 0; mtl < 4; ++mtl)                                      \
            _Pragma("unroll")                                                  \
            for (int nt = 0; nt < 4; ++nt)                                     \
                acc[(MH) * 4 + mtl][nt] =                                      \
                    __builtin_amdgcn_mfma_f32_16x16x32_bf16(                   \
                        af[mtl], bfr[nt], acc[(MH) * 4 + mtl][nt], 0, 0, 0);   \
        __builtin_amdgcn_s_setprio(0);                                         \
        asm volatile("" ::: "memory");                                         \
        __builtin_amdgcn_s_barrier();                                          \
    }

__launch_bounds__(512)
__global__ void mha_qkv_gemm(const bf16* __restrict__ hb, const bf16* __restrict__ Wt,
                             const float* __restrict__ bq, const float* __restrict__ bk,
                             const float* __restrict__ bv,
                             bf16* __restrict__ Qb, bf16* __restrict__ Kb,
                             bf16* __restrict__ Vt) {
    __shared__ __align__(16) bf16 Abuf[2][256 * 64];   // 64 KB
    __shared__ __align__(16) bf16 Bbuf[2][256 * 64];   // 64 KB

    const int tid  = threadIdx.x;
    const int lane = tid & 63;
    const int wave = tid >> 6;
    const int l16  = lane & 15;
    const int quad = (lane >> 4) & 3;
    const int wm   = wave >> 2;          // 0..1 : M half
    const int wn   = wave & 3;           // 0..3 : N quarter (= head within tile)

    const int m0  = blockIdx.x * 256;
    const int by  = blockIdx.y;          // 0..11
    const int mat = by >> 2;
    const int nc0 = (by & 3) * 256;

    const bf16* hb_blk = hb + (size_t)m0 * 1024;
    const bf16* Wb_blk = Wt + ((size_t)mat << 20) + (size_t)nc0 * 1024;

    // staging geometry: half-tile = 128 rows x 64 bf16 = 1024 chunks of 16B.
    // chunk ci = r*512 + tid (r=0,1): row = ci>>3 (rows 0..63 then 64..127),
    // LDS linear dest = ci*16B (wave-uniform base + lane*16), global source
    // chunk = (ci&7) ^ (row&7)  [row+64 has same &7 -> one cs for both r].
    const int crow = tid >> 3;                       // 0..63
    const int cs   = (tid & 7) ^ (crow & 7);
    const int swz  = l16 & 7;

    auto stage_half = [&](bf16* ldsb, const bf16* g) {
        async16(ldsb + wave * 512,        g + (size_t)crow * 1024 + cs * 8);
        async16(ldsb + 4096 + wave * 512, g + (size_t)(crow + 64) * 1024 + cs * 8);
    };

    floatx4 acc[8][4] = {};

    // prologue: stage K-tile 0 (A halves + B halves) into buf 0 -- 8 loads.
    stage_half(&Abuf[0][0],    hb_blk);
    stage_half(&Abuf[0][8192], hb_blk + 128 * 1024);
    stage_half(&Bbuf[0][0],    Wb_blk);
    stage_half(&Bbuf[0][8192], Wb_blk + 128 * 1024);

    for (int u = 0; u < 16; ++u) {
        const int cb = u & 1, nb = cb ^ 1;
        const size_t kn = (size_t)(u + 1) * 64;
        bf16x8 bfr[4];

        // ---- phase 0 (ks=0, mt 0..3) + per-K-tile counted wait ----
        if (u < 15) {
            stage_half(&Abuf[nb][0], hb_blk + kn);               // A half 0
            asm volatile("s_waitcnt vmcnt(2)" ::: "memory");     // K-tile u landed
        } else {
            asm volatile("s_waitcnt vmcnt(0)" ::: "memory");     // tail drain
        }
        __builtin_amdgcn_s_barrier();
        asm volatile("" ::: "memory");
        GPHASE(0, 0, 1)

        // ---- phase 1 (ks=0, mt 4..7) ----
        if (u < 15) stage_half(&Abuf[nb][8192], hb_blk + 128 * 1024 + kn);
        GPHASE(0, 1, 0)

        // ---- phase 2 (ks=1, mt 0..3) ----
        if (u < 15) stage_half(&Bbuf[nb][0], Wb_blk + kn);
        GPHASE(1, 0, 1)

        // ---- phase 3 (ks=1, mt 4..7) ----
        if (u < 15) stage_half(&Bbuf[nb][8192], Wb_blk + 128 * 1024 + kn);
        GPHASE(1, 1, 0)
    }

    // ---- epilogue: R4-verified scalar stores; wave wn owns one head ----
    const float* bias = (mat == 0) ? bq : (mat == 1) ? bk : bv;
    const int head = (nc0 >> 6) + wn;
#pragma unroll
    for (int nt = 0; nt < 4; ++nt) {
        const int d  = nt * 16 + l16;
        const float bb = bias[nc0 + wn * 64 + d];
#pragma unroll
        for (int mt = 0; mt < 8; ++mt)
#pragma unroll
            for (int r = 0; r < 4; ++r) {
                const int srow = m0 + wm * 128 + mt * 16 + quad * 4 + r;
                float v = acc[mt][nt][r] + bb;
                if (mat == 0)
                    Qb[((size_t)head * SEQ + srow) * HEAD_DIM + d] = (bf16)(v * QSCALE);
                else if (mat == 1)
                    Kb[((size_t)head * SEQ + srow) * HEAD_DIM + d] = (bf16)v;
                else
                    Vt[((size_t)head * HEAD_DIM + d) * SEQ + srow] = (bf16)v;
            }
    }
}

// ---------------------------------------------------------------------------
// Attention (R4-exact, verified): 8 waves x 32 q-rows (256 q/block, 1
// block/CU), 32x32x16 MFMA, in-register P transpose, counted-vmcnt 3-buffer
// pipeline, XCD-head swizzle (K/V L2-resident, FETCH 69.7->12.3MB).
// R4/R5 falsified drain- and occupancy-theories; structure-bound ~95-99us.
// ---------------------------------------------------------------------------
__launch_bounds__(512)
__global__ void mha_attn(const bf16* __restrict__ Qb, const bf16* __restrict__ Kb,
                         const bf16* __restrict__ Vt, float* __restrict__ out) {
    __shared__ __align__(16) bf16 Ks[3][64 * 64];       // 24 KB
    __shared__ __align__(16) bf16 Vs[3][64 * 64];       // 24 KB (d-major V^T)

    const int lane = threadIdx.x & 63;
    const int wave = threadIdx.x >> 6;
    const int l31  = lane & 31;
    const int hi   = lane >> 5;

    // XCD-head swizzle: 256 blocks; XCD k (= bid%8) gets heads {2k, 2k+1}
    const int bid = blockIdx.x;
    const int hh  = 2 * (bid & 7) + ((bid >> 3) & 1);
    const int qx  = bid >> 4;
    const int q0  = qx * 256 + wave * 32;

    const bf16* Qh = Qb + (size_t)hh * SEQ * HEAD_DIM;
    const bf16* Kh = Kb + (size_t)hh * SEQ * HEAD_DIM;
    const bf16* Vh = Vt + (size_t)hh * HEAD_DIM * SEQ;

    const int sg   = wave * 64 + lane;           // 0..511
    const int srow = sg >> 3;                    // 0..63
    const int sgc  = (sg & 7) ^ (srow & 7);

    bf16x8 qf[4];
#pragma unroll
    for (int ks = 0; ks < 4; ++ks)
        qf[ks] = *(const bf16x8*)(Qh + (size_t)(q0 + l31) * HEAD_DIM + ks * 16 + hi * 8);

    bf16x8 vone;
#pragma unroll
    for (int i = 0; i < 8; ++i) vone[i] = (bf16)1.0f;

    floatx16 o0 = {}, o1 = {}, ol = {};
    const int swz = l31 & 7;

    async16(&Ks[0][wave * 512], Kh + (size_t)srow * HEAD_DIM + sgc * 8);
    async16(&Vs[0][wave * 512], Vh + (size_t)srow * SEQ + 0 + sgc * 8);
    async16(&Ks[1][wave * 512], Kh + (size_t)(64 + srow) * HEAD_DIM + sgc * 8);
    async16(&Vs[1][wave * 512], Vh + (size_t)srow * SEQ + 64 + sgc * 8);
    asm volatile("s_waitcnt vmcnt(0)" ::: "memory");
    __builtin_amdgcn_s_barrier();

    int cur = 0;
    for (int t = 0; t < SEQ / 64; ++t) {
        int pre = cur + 2; if (pre >= 3) pre -= 3;
        if (t + 2 < SEQ / 64) {
            const int tg = (t + 2) * 64;
            async16(&Ks[pre][wave * 512], Kh + (size_t)(tg + srow) * HEAD_DIM + sgc * 8);
            async16(&Vs[pre][wave * 512], Vh + (size_t)srow * SEQ + tg + sgc * 8);
        }
        if (t < SEQ / 64 - 2)       asm volatile("s_waitcnt vmcnt(4)" ::: "memory");
        else if (t == SEQ / 64 - 2) asm volatile("s_waitcnt vmcnt(2)" ::: "memory");
        else                        asm volatile("s_waitcnt vmcnt(0)" ::: "memory");
        __builtin_amdgcn_s_barrier();
        asm volatile("" ::: "memory");

        bf16x8 kf[2][4];
#pragma unroll
        for (int tt = 0; tt < 2; ++tt)
#pragma unroll
            for (int ks = 0; ks < 4; ++ks)
                kf[tt][ks] = *(const bf16x8*)(&Ks[cur][(tt * 32 + l31) * 64
                                              + (((ks * 2 + hi) ^ swz) * 8)]);

        floatx16 s0 = {}, s1 = {};
#pragma unroll
        for (int ks = 0; ks < 4; ++ks)
            s0 = __builtin_amdgcn_mfma_f32_32x32x16_bf16(kf[0][ks], qf[ks], s0, 0, 0, 0);
#pragma unroll
        for (int ks = 0; ks < 4; ++ks)
            s1 = __builtin_amdgcn_mfma_f32_32x32x16_bf16(kf[1][ks], qf[ks], s1, 0, 0, 0);

        bf16x8 vf[2][4];
#pragma unroll
        for (int dt = 0; dt < 2; ++dt)
#pragma unroll
            for (int sl = 0; sl < 4; ++sl)
                vf[dt][sl] = *(const bf16x8*)(&Vs[cur][(dt * 32 + l31) * 64
                                              + (((sl * 2 + hi) ^ swz) * 8)]);

        bf16x8 pa[4];
#pragma unroll
        for (int sl = 0; sl < 4; ++sl) {
            const floatx16 sv = (sl < 2) ? s0 : s1;
            const int rb = 8 * (sl & 1);
            float p0 = __builtin_amdgcn_exp2f(sv[rb + 0]);
            float p1 = __builtin_amdgcn_exp2f(sv[rb + 1]);
            float p2 = __builtin_amdgcn_exp2f(sv[rb + 2]);
            float p3 = __builtin_amdgcn_exp2f(sv[rb + 3]);
            float p4 = __builtin_amdgcn_exp2f(sv[rb + 4]);
            float p5 = __builtin_amdgcn_exp2f(sv[rb + 5]);
            float p6 = __builtin_amdgcn_exp2f(sv[rb + 6]);
            float p7 = __builtin_amdgcn_exp2f(sv[rb + 7]);
            unsigned u0 = cvtpk_bf16(p0, p1);
            unsigned u1 = cvtpk_bf16(p2, p3);
            unsigned u2 = cvtpk_bf16(p4, p5);
            unsigned u3 = cvtpk_bf16(p6, p7);
            permswap(u0, u2);
            permswap(u1, u3);
            uint32x4 w;
            w[0] = u0; w[1] = u1; w[2] = u2; w[3] = u3;
            pa[sl] = __builtin_bit_cast(bf16x8, w);
        }

#pragma unroll
        for (int sl = 0; sl < 4; ++sl) {
            o0 = __builtin_amdgcn_mfma_f32_32x32x16_bf16(pa[sl], vf[0][sl], o0, 0, 0, 0);
            o1 = __builtin_amdgcn_mfma_f32_32x32x16_bf16(pa[sl], vf[1][sl], o1, 0, 0, 0);
            ol = __builtin_amdgcn_mfma_f32_32x32x16_bf16(pa[sl], vone, ol, 0, 0, 0);
        }

        asm volatile("" ::: "memory");
        __builtin_amdgcn_s_barrier();      // reads of buf[cur] done before restage
        cur = cur + 1; if (cur == 3) cur = 0;
    }

#pragma unroll
    for (int r = 0; r < 16; ++r) {
        const int q = q0 + (r & 3) + 8 * (r >> 2) + 4 * hi;
        const float inv = 1.0f / ol[r];
        out[(size_t)q * (NUM_HEADS * HEAD_DIM) + hh * 64 + l31]      = o0[r] * inv;
        out[(size_t)q * (NUM_HEADS * HEAD_DIM) + hh * 64 + 32 + l31] = o1[r] * inv;
    }
}

extern "C" void kernel_launch(void* const* d_in, const int* in_sizes, int n_in,
                              void* d_out, int out_size, void* d_ws, size_t ws_size,
                              hipStream_t stream) {
    const float* h  = (const float*)d_in[0];
    const float* Wq = (const float*)d_in[1];
    const float* Wk = (const float*)d_in[2];
    const float* Wv = (const float*)d_in[3];
    const float* bq = (const float*)d_in[4];
    const float* bk = (const float*)d_in[5];
    const float* bv = (const float*)d_in[6];
    float* out = (float*)d_out;

    char* ws = (char*)d_ws;
    const size_t MB = 1024 * 1024;
    bf16* hb = (bf16*)(ws);
    bf16* Wt = (bf16*)(ws + 8 * MB);
    bf16* Qb = (bf16*)(ws + 14 * MB);
    bf16* Kb = (bf16*)(ws + 22 * MB);
    bf16* Vt = (bf16*)(ws + 30 * MB);

    mha_conv_h<<<(SEQ * IN_DIM / 4) / 256, 256, 0, stream>>>(h, hb);
    mha_conv_wt<<<dim3(16, 16, 3), 256, 0, stream>>>(Wq, Wk, Wv, Wt);
    // 256x256 tiles: (4096/256) x (3072/256) = 16 x 12 = 192 blocks, 512 thr.
    mha_qkv_gemm<<<dim3(16, 12), 512, 0, stream>>>(
        hb, Wt, bq, bk, bv, Qb, Kb, Vt);
    mha_attn<<<dim3((SEQ / 256) * NUM_HEADS), 512, 0, stream>>>(Qb, Kb, Vt, out);
}